// Round 9
// baseline (620.993 us; speedup 1.0000x reference)
//
#include <hip/hip_runtime.h>

using bf16x8 = __attribute__((ext_vector_type(8))) short;
using f32x4  = __attribute__((ext_vector_type(4))) float;

#define B_SZ 8192
#define D_SZ 1024
#define H_SZ 128
#define C_SZ 256
#define T_SZ 16

__device__ __forceinline__ unsigned short f2bf(float f) {
  unsigned int u = __float_as_uint(f);
  return (unsigned short)((u + 0x7fffu + ((u >> 16) & 1u)) >> 16);
}

// ------- transpose+cast: src[t][R][C] f32 -> dst[t][C][R] bf16 (k-major for MFMA) -------
__global__ __launch_bounds__(256) void transpose_cast_kernel(const float* __restrict__ src,
                                                             unsigned short* __restrict__ dst,
                                                             int R, int C, int cshift) {
  __shared__ float tile[32][257];
  const int t = blockIdx.y;
  const int r0 = blockIdx.x * 32;
  const float* s = src + ((size_t)t * R + r0) * C;
  const int n = 32 * C;
  for (int idx = threadIdx.x; idx < n; idx += 256)
    tile[idx >> cshift][idx & (C - 1)] = s[idx];
  __syncthreads();
  unsigned short* d = dst + (size_t)t * C * R + r0;
  for (int idx = threadIdx.x; idx < n; idx += 256) {
    int cc = idx >> 5, rr = idx & 31;
    d[(size_t)cc * R + rr] = f2bf(tile[rr][cc]);
  }
}

// ------ router + x-cast fused: probs = softmax(x@Wr+br); xb = bf16(x) ------
__global__ __launch_bounds__(256) void router_cast_kernel(const float* __restrict__ x,
                                                          const float* __restrict__ Wr,
                                                          const float* __restrict__ br,
                                                          float* __restrict__ out0,
                                                          unsigned short* __restrict__ xb) {
  const int lane = threadIdx.x & 63;
  const int wid  = threadIdx.x >> 6;
  const int brow = blockIdx.x * 16 + wid * 4;
  float acc[4][16];
#pragma unroll
  for (int r = 0; r < 4; ++r)
#pragma unroll
    for (int tt = 0; tt < 16; ++tt) acc[r][tt] = 0.f;

  for (int it = 0; it < 16; ++it) {
    const int d = it * 64 + lane;
    const float4* w4 = (const float4*)(Wr + (size_t)d * 16);
    float4 wa = w4[0], wb = w4[1], wc = w4[2], wd = w4[3];
    const float wv[16] = {wa.x, wa.y, wa.z, wa.w, wb.x, wb.y, wb.z, wb.w,
                          wc.x, wc.y, wc.z, wc.w, wd.x, wd.y, wd.z, wd.w};
#pragma unroll
    for (int r = 0; r < 4; ++r) {
      const float xv = x[(size_t)(brow + r) * 1024 + d];
      xb[(size_t)(brow + r) * 1024 + d] = f2bf(xv);
#pragma unroll
      for (int tt = 0; tt < 16; ++tt) acc[r][tt] += xv * wv[tt];
    }
  }
#pragma unroll
  for (int off = 32; off >= 1; off >>= 1) {
#pragma unroll
    for (int r = 0; r < 4; ++r)
#pragma unroll
      for (int tt = 0; tt < 16; ++tt) acc[r][tt] += __shfl_xor(acc[r][tt], off);
  }
  if (lane == 0) {
#pragma unroll
    for (int r = 0; r < 4; ++r) {
      float v[16]; float m = -1e30f;
#pragma unroll
      for (int tt = 0; tt < 16; ++tt) { v[tt] = acc[r][tt] + br[tt]; m = fmaxf(m, v[tt]); }
      float ssum = 0.f;
#pragma unroll
      for (int tt = 0; tt < 16; ++tt) { v[tt] = __expf(v[tt] - m); ssum += v[tt]; }
      const float inv = 1.0f / ssum;
      float4* o = (float4*)(out0 + (size_t)(brow + r) * 16);
      o[0] = make_float4(v[0] * inv, v[1] * inv, v[2] * inv, v[3] * inv);
      o[1] = make_float4(v[4] * inv, v[5] * inv, v[6] * inv, v[7] * inv);
      o[2] = make_float4(v[8] * inv, v[9] * inv, v[10] * inv, v[11] * inv);
      o[3] = make_float4(v[12] * inv, v[13] * inv, v[14] * inv, v[15] * inv);
    }
  }
}

// ---------------- ABLATION v2 (rank-visible): expert_kernel<V, REP> ----------------
// V0 full | V1 feed-only | V2 LDS+MFMA only | V3 full-fc1, no fc2 | V4 ds_read-only
// REP repeats the fc1 K-loop so variants outrank the 76us harness fills in top-5.
#define SW_REG 65536

template <int V, int REP>
__global__ __launch_bounds__(512, 2) void expert_kernel(
    const unsigned short* __restrict__ xb, const unsigned short* __restrict__ w1b,
    const unsigned short* __restrict__ w2b, const float* __restrict__ b1,
    const float* __restrict__ b2, const float* __restrict__ probs,
    float* __restrict__ out1) {
  __shared__ __align__(16) char smem[98304];
  const int tid  = threadIdx.x;
  const int lane = tid & 63;
  const int w    = tid >> 6;   // 0..7
  const int l16  = lane & 15;
  const int l4   = lane >> 4;  // 0..3

  const int bid = blockIdx.x;
  const int lid = (bid & 7) * 64 + (bid >> 3);
  const int t   = lid & 15;
  const int b0  = (lid >> 4) * 256;

  const unsigned short* gp[6];
  unsigned int ldo[6];
#pragma unroll
  for (int it = 0; it < 6; ++it) {
    if (it < 4) {
      const unsigned int o = (unsigned int)w * 4096u + (unsigned int)it * 1024u + (unsigned int)lane * 16u;
      const int row = (int)(o >> 7);
      const int cb  = (int)((o & 127u) ^ (((unsigned)row & 7u) << 4));
      gp[it]  = xb + (size_t)(b0 + row) * 1024 + (cb >> 1);
      ldo[it] = o;
    } else {
      const unsigned int o = (unsigned int)w * 2048u + (unsigned int)(it - 4) * 1024u + (unsigned int)lane * 16u;
      const int row = (int)(o >> 7);
      const int cb  = (int)((o & 127u) ^ (((unsigned)row & 7u) << 4));
      gp[it]  = w1b + (size_t)(t * 128 + row) * 1024 + (cb >> 1);
      ldo[it] = o;
    }
  }

#define STAGE(curbuf, kt)                                                              \
  {                                                                                    \
    _Pragma("unroll")                                                                  \
    for (int it = 0; it < 6; ++it) {                                                   \
      const unsigned short* g = gp[it] + (kt) * 64;                                    \
      char* dd = smem + (it < 4 ? (curbuf) * 32768 + (int)ldo[it]                      \
                                : SW_REG + (curbuf) * 16384 + (int)ldo[it]);           \
      __builtin_amdgcn_global_load_lds(                                                \
          (const __attribute__((address_space(1))) unsigned int*)g,                    \
          (__attribute__((address_space(3))) unsigned int*)dd, 16, 0, 0);              \
    }                                                                                  \
  }

  const int wn = w & 1;
  const int wm = w >> 1;
  f32x4 acc1[4][4] = {};

#define FC1_COMPUTE(curbuf)                                                            \
  {                                                                                    \
    const int bx_base = (curbuf) * 32768;                                              \
    const int aw_base = SW_REG + (curbuf) * 16384;                                     \
    _Pragma("unroll")                                                                  \
    for (int ks = 0; ks < 2; ++ks) {                                                   \
      const int cb = ks * 64 + l4 * 16;                                                \
      bf16x8 aw[4], bx[4];                                                             \
      _Pragma("unroll")                                                                \
      for (int ni = 0; ni < 4; ++ni) {                                                 \
        const int row = wn * 64 + ni * 16 + l16;                                       \
        aw[ni] = *(const bf16x8*)(smem + aw_base + (row << 7) + (cb ^ ((row & 7) << 4)));\
      }                                                                                \
      _Pragma("unroll")                                                                \
      for (int mi = 0; mi < 4; ++mi) {                                                 \
        const int row = wm * 64 + mi * 16 + l16;                                       \
        bx[mi] = *(const bf16x8*)(smem + bx_base + (row << 7) + (cb ^ ((row & 7) << 4)));\
      }                                                                                \
      _Pragma("unroll")                                                                \
      for (int ni = 0; ni < 4; ++ni)                                                   \
        _Pragma("unroll")                                                              \
        for (int mi = 0; mi < 4; ++mi)                                                 \
          acc1[ni][mi] = __builtin_amdgcn_mfma_f32_16x16x32_bf16(aw[ni], bx[mi], acc1[ni][mi], 0, 0, 0); \
    }                                                                                  \
  }

  // ds_read-only with keep-alive sinks (rule 17: no DCE, no MFMA)
#define FC1_READONLY(curbuf)                                                           \
  {                                                                                    \
    const int bx_base = (curbuf) * 32768;                                              \
    const int aw_base = SW_REG + (curbuf) * 16384;                                     \
    _Pragma("unroll")                                                                  \
    for (int ks = 0; ks < 2; ++ks) {                                                   \
      const int cb = ks * 64 + l4 * 16;                                                \
      _Pragma("unroll")                                                                \
      for (int ni = 0; ni < 4; ++ni) {                                                 \
        const int row = wn * 64 + ni * 16 + l16;                                       \
        bf16x8 v = *(const bf16x8*)(smem + aw_base + (row << 7) + (cb ^ ((row & 7) << 4)));\
        asm volatile("" :: "v"(*(f32x4*)&v));                                          \
      }                                                                                \
      _Pragma("unroll")                                                                \
      for (int mi = 0; mi < 4; ++mi) {                                                 \
        const int row = wm * 64 + mi * 16 + l16;                                       \
        bf16x8 v = *(const bf16x8*)(smem + bx_base + (row << 7) + (cb ^ ((row & 7) << 4)));\
        asm volatile("" :: "v"(*(f32x4*)&v));                                          \
      }                                                                                \
    }                                                                                  \
  }

#pragma unroll 1
  for (int rep = 0; rep < REP; ++rep) {
    STAGE(0, 0);
    __syncthreads();
    int cur = 0;
    for (int kt = 0; kt < 15; ++kt) {
      if constexpr (V != 2) { STAGE(cur ^ 1, kt + 1); }
      if constexpr (V != 1 && V != 4) { FC1_COMPUTE(cur); }
      if constexpr (V == 4) { FC1_READONLY(cur); }
      __syncthreads();
      cur ^= 1;
    }
    if constexpr (V != 1 && V != 4) { FC1_COMPUTE(cur); }
    if constexpr (V == 4) { FC1_READONLY(cur); }
    __syncthreads();
  }

  // fc1 epilogue: +b1, relu, cvt bf16, write hT -> sH[m][k=n]
#pragma unroll
  for (int ni = 0; ni < 4; ++ni) {
    const int n0 = wn * 64 + ni * 16 + l4 * 4;
    float bb[4];
#pragma unroll
    for (int r = 0; r < 4; ++r) bb[r] = b1[t * 128 + n0 + r];
#pragma unroll
    for (int mi = 0; mi < 4; ++mi) {
      const int m = wm * 64 + mi * 16 + l16;
      unsigned int pk[2];
#pragma unroll
      for (int h = 0; h < 2; ++h) {
        float v0 = fmaxf(acc1[ni][mi][2 * h + 0] + bb[2 * h + 0], 0.f);
        float v1 = fmaxf(acc1[ni][mi][2 * h + 1] + bb[2 * h + 1], 0.f);
        pk[h] = (unsigned int)f2bf(v0) | ((unsigned int)f2bf(v1) << 16);
      }
      const int byte = (m << 8) + ((n0 * 2) ^ ((m & 7) << 4));
      *(uint2*)(smem + byte) = make_uint2(pk[0], pk[1]);
    }
  }
  __syncthreads();

  // fc2
  const int wm2 = w >> 1;
  const int wc  = w & 1;
  f32x4 acc2[4][8] = {};
  const unsigned short* w2t = w2b + (size_t)t * C_SZ * H_SZ;

  if constexpr (V != 3) {
#pragma unroll
    for (int ks = 0; ks < 4; ++ks) {
      const int cb = ks * 64 + l4 * 16;
      bf16x8 ah[4];
#pragma unroll
      for (int mi = 0; mi < 4; ++mi) {
        const int row = wm2 * 64 + mi * 16 + l16;
        ah[mi] = *(const bf16x8*)(smem + (row << 8) + (cb ^ ((row & 7) << 4)));
      }
#pragma unroll
      for (int ci = 0; ci < 8; ++ci) {
        const int c = wc * 128 + ci * 16 + l16;
        bf16x8 bw = *(const bf16x8*)(w2t + (size_t)c * 128 + ks * 32 + l4 * 8);
#pragma unroll
        for (int mi = 0; mi < 4; ++mi)
          acc2[mi][ci] = __builtin_amdgcn_mfma_f32_16x16x32_bf16(ah[mi], bw, acc2[mi][ci], 0, 0, 0);
      }
    }
  }

  // fc2 epilogue
  const size_t outbase = (size_t)t * (size_t)(B_SZ * C_SZ);
#pragma unroll
  for (int mi = 0; mi < 4; ++mi) {
    const int m0 = wm2 * 64 + mi * 16 + l4 * 4;
    float pv[4];
#pragma unroll
    for (int r = 0; r < 4; ++r) pv[r] = probs[(size_t)(b0 + m0 + r) * 16 + t];
#pragma unroll
    for (int ci = 0; ci < 8; ++ci) {
      const int c = wc * 128 + ci * 16 + l16;
      const float bias = b2[t * 256 + c];
#pragma unroll
      for (int r = 0; r < 4; ++r)
        out1[outbase + (size_t)(b0 + m0 + r) * 256 + c] = (acc2[mi][ci][r] + bias) * pv[r];
    }
  }
}

extern "C" void kernel_launch(void* const* d_in, const int* in_sizes, int n_in,
                              void* d_out, int out_size, void* d_ws, size_t ws_size,
                              hipStream_t stream) {
  const float* x  = (const float*)d_in[0];
  const float* Wr = (const float*)d_in[1];
  const float* br = (const float*)d_in[2];
  const float* W1 = (const float*)d_in[3];
  const float* b1 = (const float*)d_in[4];
  const float* W2 = (const float*)d_in[5];
  const float* b2 = (const float*)d_in[6];
  float* out0 = (float*)d_out;                       // [B][T] probs
  float* out1 = out0 + (size_t)B_SZ * T_SZ;          // [T][B][C] preds

  char* ws = (char*)d_ws;
  unsigned short* xb  = (unsigned short*)ws;                                // 16 MiB [B][D]
  unsigned short* w1b = (unsigned short*)(ws + (size_t)16777216);           // 4 MiB  [T][H][D]
  unsigned short* w2b = (unsigned short*)(ws + (size_t)16777216 + 4194304); // 1 MiB  [T][C][H]

  router_cast_kernel<<<B_SZ / 16, 256, 0, stream>>>(x, Wr, br, out0, xb);
  transpose_cast_kernel<<<dim3(D_SZ / 32, T_SZ), 256, 0, stream>>>(W1, w1b, D_SZ, H_SZ, 7);
  transpose_cast_kernel<<<dim3(H_SZ / 32, T_SZ), 256, 0, stream>>>(W2, w2b, H_SZ, C_SZ, 8);

  // --- ablation dispatches, REP=4 (garbage out1, overwritten by V0 below) ---
  expert_kernel<1, 4><<<512, 512, 0, stream>>>(xb, w1b, w2b, b1, b2, out0, out1); // feed only
  expert_kernel<2, 4><<<512, 512, 0, stream>>>(xb, w1b, w2b, b1, b2, out0, out1); // LDS+MFMA only
  expert_kernel<4, 4><<<512, 512, 0, stream>>>(xb, w1b, w2b, b1, b2, out0, out1); // ds_read only
  expert_kernel<3, 4><<<512, 512, 0, stream>>>(xb, w1b, w2b, b1, b2, out0, out1); // full fc1, no fc2
  // --- final, correct ---
  expert_kernel<0, 1><<<512, 512, 0, stream>>>(xb, w1b, w2b, b1, b2, out0, out1);
}

// Round 10
// 115.788 us; speedup vs baseline: 5.3632x; 5.3632x over previous
//
#include <hip/hip_runtime.h>

using bf16x8 = __attribute__((ext_vector_type(8))) short;
using f32x4  = __attribute__((ext_vector_type(4))) float;

#define B_SZ 8192
#define D_SZ 1024
#define H_SZ 128
#define C_SZ 256
#define T_SZ 16

__device__ __forceinline__ unsigned short f2bf(float f) {
  unsigned int u = __float_as_uint(f);
  return (unsigned short)((u + 0x7fffu + ((u >> 16) & 1u)) >> 16);
}

// ------- transpose+cast: src[t][R][C] f32 -> dst[t][C][R] bf16 (k-major for MFMA) -------
__global__ __launch_bounds__(256) void transpose_cast_kernel(const float* __restrict__ src,
                                                             unsigned short* __restrict__ dst,
                                                             int R, int C, int cshift) {
  __shared__ float tile[32][257];
  const int t = blockIdx.y;
  const int r0 = blockIdx.x * 32;
  const float* s = src + ((size_t)t * R + r0) * C;
  const int n = 32 * C;
  for (int idx = threadIdx.x; idx < n; idx += 256)
    tile[idx >> cshift][idx & (C - 1)] = s[idx];
  __syncthreads();
  unsigned short* d = dst + (size_t)t * C * R + r0;
  for (int idx = threadIdx.x; idx < n; idx += 256) {
    int cc = idx >> 5, rr = idx & 31;
    d[(size_t)cc * R + rr] = f2bf(tile[rr][cc]);
  }
}

// ------ router + x-cast fused: probs = softmax(x@Wr+br); xb = bf16(x) ------
__global__ __launch_bounds__(256) void router_cast_kernel(const float* __restrict__ x,
                                                          const float* __restrict__ Wr,
                                                          const float* __restrict__ br,
                                                          float* __restrict__ out0,
                                                          unsigned short* __restrict__ xb) {
  const int lane = threadIdx.x & 63;
  const int wid  = threadIdx.x >> 6;
  const int brow = blockIdx.x * 16 + wid * 4;
  float acc[4][16];
#pragma unroll
  for (int r = 0; r < 4; ++r)
#pragma unroll
    for (int tt = 0; tt < 16; ++tt) acc[r][tt] = 0.f;

  for (int it = 0; it < 16; ++it) {
    const int d = it * 64 + lane;
    const float4* w4 = (const float4*)(Wr + (size_t)d * 16);
    float4 wa = w4[0], wb = w4[1], wc = w4[2], wd = w4[3];
    const float wv[16] = {wa.x, wa.y, wa.z, wa.w, wb.x, wb.y, wb.z, wb.w,
                          wc.x, wc.y, wc.z, wc.w, wd.x, wd.y, wd.z, wd.w};
#pragma unroll
    for (int r = 0; r < 4; ++r) {
      const float xv = x[(size_t)(brow + r) * 1024 + d];
      xb[(size_t)(brow + r) * 1024 + d] = f2bf(xv);
#pragma unroll
      for (int tt = 0; tt < 16; ++tt) acc[r][tt] += xv * wv[tt];
    }
  }
#pragma unroll
  for (int off = 32; off >= 1; off >>= 1) {
#pragma unroll
    for (int r = 0; r < 4; ++r)
#pragma unroll
      for (int tt = 0; tt < 16; ++tt) acc[r][tt] += __shfl_xor(acc[r][tt], off);
  }
  if (lane == 0) {
#pragma unroll
    for (int r = 0; r < 4; ++r) {
      float v[16]; float m = -1e30f;
#pragma unroll
      for (int tt = 0; tt < 16; ++tt) { v[tt] = acc[r][tt] + br[tt]; m = fmaxf(m, v[tt]); }
      float ssum = 0.f;
#pragma unroll
      for (int tt = 0; tt < 16; ++tt) { v[tt] = __expf(v[tt] - m); ssum += v[tt]; }
      const float inv = 1.0f / ssum;
      float4* o = (float4*)(out0 + (size_t)(brow + r) * 16);
      o[0] = make_float4(v[0] * inv, v[1] * inv, v[2] * inv, v[3] * inv);
      o[1] = make_float4(v[4] * inv, v[5] * inv, v[6] * inv, v[7] * inv);
      o[2] = make_float4(v[8] * inv, v[9] * inv, v[10] * inv, v[11] * inv);
      o[3] = make_float4(v[12] * inv, v[13] * inv, v[14] * inv, v[15] * inv);
    }
  }
}

// ---------------- fused expert v2: per (128 rows, 2 tasks) ----------------
// Traffic redesign (R9 ablation: all paths near-roofline at old geometry):
//  - x fragments read per-lane from GLOBAL (L2-hot) -> no sX staging, no x ds_reads
//  - block = 128 m-rows x 2 tasks (BN=256); 4 waves, per-wave 64m x 128n (AI 42.7 FLOP/B)
//  - LDS: sW dbuf 2x32KB [256n][64k]; sH [128m][256n] 64KB aliases sW; 2 blocks/CU
__global__ __launch_bounds__(256, 2) void expert_kernel(
    const unsigned short* __restrict__ xb, const unsigned short* __restrict__ w1b,
    const unsigned short* __restrict__ w2b, const float* __restrict__ b1,
    const float* __restrict__ b2, const float* __restrict__ probs,
    float* __restrict__ out1) {
  __shared__ __align__(16) char smem[65536];
  const int tid  = threadIdx.x;
  const int lane = tid & 63;
  const int w    = tid >> 6;   // 0..3
  const int l16  = lane & 15;
  const int l4   = lane >> 4;  // 0..3

  // bijective swizzle: 512 blocks = 8 xcd x (8 mloc x 8 ngrp), ngrp fastest (x-tile reuse in-XCD)
  const int bid  = blockIdx.x;
  const int xcd  = bid & 7;
  const int i    = bid >> 3;       // 0..63
  const int ngrp = i & 7;          // task pair
  const int mloc = i >> 3;         // 0..7
  const int t0   = ngrp * 2;
  const int b0   = (xcd * 8 + mloc) * 128;

  const int wm = w >> 1;           // m-half (64 rows)
  const int wn = w & 1;            // task within pair
  const int t  = t0 + wn;

  // ---- W1 staging: 8 x 16B gload_lds per thread per kt (32KB) ----
  // linear LDS dest o = it*4096 + tid*16; inverse-swizzled global source
  unsigned int goff[8], ldo[8];
#pragma unroll
  for (int it = 0; it < 8; ++it) {
    const unsigned int o = (unsigned int)it * 4096u + (unsigned int)tid * 16u;
    const unsigned int row = o >> 7;
    const unsigned int cb  = (o & 127u) ^ ((row & 7u) << 4);
    goff[it] = row * 1024u + (cb >> 1);
    ldo[it]  = o;
  }
  const unsigned short* w1base = w1b + (size_t)t0 * 128 * 1024;

#define STAGE(curbuf, kt)                                                              \
  {                                                                                    \
    _Pragma("unroll")                                                                  \
    for (int it = 0; it < 8; ++it) {                                                   \
      const unsigned short* g = w1base + goff[it] + (kt) * 64;                         \
      char* dd = smem + (curbuf) * 32768 + (int)ldo[it];                               \
      __builtin_amdgcn_global_load_lds(                                                \
          (const __attribute__((address_space(1))) unsigned int*)g,                    \
          (__attribute__((address_space(3))) unsigned int*)dd, 16, 0, 0);              \
    }                                                                                  \
  }

  // per-lane x row base (bx frag: row = b0 + wm*64 + mi*16 + l16, 16B at k-offset)
  const unsigned short* xr = xb + (size_t)(b0 + wm * 64 + l16) * 1024 + l4 * 8;

  f32x4 acc1[8][4] = {};

  STAGE(0, 0);
  __syncthreads();
  int buf = 0;
  for (int kt = 0; kt < 16; ++kt) {
    if (kt < 15) STAGE(buf ^ 1, kt + 1);
    // x fragments from global (L2): 8 x 16B per lane per kt
    bf16x8 bx[2][4];
#pragma unroll
    for (int ks = 0; ks < 2; ++ks)
#pragma unroll
      for (int mi = 0; mi < 4; ++mi)
        bx[ks][mi] = *(const bf16x8*)(xr + mi * 16384 + kt * 64 + ks * 32);
#pragma unroll
    for (int ks = 0; ks < 2; ++ks) {
      bf16x8 aw[8];
#pragma unroll
      for (int ni = 0; ni < 8; ++ni) {
        const int row = wn * 128 + ni * 16 + l16;
        aw[ni] = *(const bf16x8*)(smem + buf * 32768 + (row << 7) +
                                  ((ks * 64 + l4 * 16) ^ ((row & 7) << 4)));
      }
      __builtin_amdgcn_s_setprio(1);
#pragma unroll
      for (int ni = 0; ni < 8; ++ni)
#pragma unroll
        for (int mi = 0; mi < 4; ++mi)
          acc1[ni][mi] = __builtin_amdgcn_mfma_f32_16x16x32_bf16(aw[ni], bx[ks][mi], acc1[ni][mi], 0, 0, 0);
      __builtin_amdgcn_s_setprio(0);
    }
    __syncthreads();
    buf ^= 1;
  }

  // fc1 epilogue: +b1, relu, bf16, write hT -> sH[m][256n] (aliases sW; swizzled 8B stores)
#pragma unroll
  for (int ni = 0; ni < 8; ++ni) {
    const int n0 = ni * 16 + l4 * 4;
    float bb[4];
#pragma unroll
    for (int r = 0; r < 4; ++r) bb[r] = b1[t * 128 + n0 + r];
#pragma unroll
    for (int mi = 0; mi < 4; ++mi) {
      const int m = wm * 64 + mi * 16 + l16;
      unsigned int pk[2];
#pragma unroll
      for (int h = 0; h < 2; ++h) {
        float v0 = fmaxf(acc1[ni][mi][2 * h + 0] + bb[2 * h + 0], 0.f);
        float v1 = fmaxf(acc1[ni][mi][2 * h + 1] + bb[2 * h + 1], 0.f);
        pk[h] = (unsigned int)f2bf(v0) | ((unsigned int)f2bf(v1) << 16);
      }
      const int inner = (wn * 256 + n0 * 2) ^ ((m & 7) << 4);
      *(uint2*)(smem + (m << 9) + inner) = make_uint2(pk[0], pk[1]);
    }
  }
  __syncthreads();

  // fc2: per wave: task t, rows wm*64..+64, loop 2 c-halves of 128
  const unsigned short* w2t = w2b + (size_t)t * C_SZ * H_SZ;
  const size_t outbase = (size_t)t * (size_t)(B_SZ * C_SZ);
#pragma unroll
  for (int ch = 0; ch < 2; ++ch) {
    f32x4 acc2[4][8] = {};
#pragma unroll
    for (int ks = 0; ks < 4; ++ks) {
      bf16x8 ah[4];
#pragma unroll
      for (int mi = 0; mi < 4; ++mi) {
        const int row = wm * 64 + mi * 16 + l16;
        const int inner = (wn * 256 + ks * 64 + l4 * 16) ^ ((row & 7) << 4);
        ah[mi] = *(const bf16x8*)(smem + (row << 9) + inner);
      }
#pragma unroll
      for (int ci = 0; ci < 8; ++ci) {
        const int c = ch * 128 + ci * 16 + l16;
        bf16x8 bw = *(const bf16x8*)(w2t + (size_t)c * 128 + ks * 32 + l4 * 8);
#pragma unroll
        for (int mi = 0; mi < 4; ++mi)
          acc2[mi][ci] = __builtin_amdgcn_mfma_f32_16x16x32_bf16(ah[mi], bw, acc2[mi][ci], 0, 0, 0);
      }
    }
    // epilogue: +b2, * probs, store f32
#pragma unroll
    for (int mi = 0; mi < 4; ++mi) {
      const int m0 = wm * 64 + mi * 16 + l4 * 4;
      float pv[4];
#pragma unroll
      for (int r = 0; r < 4; ++r) pv[r] = probs[(size_t)(b0 + m0 + r) * 16 + t];
#pragma unroll
      for (int ci = 0; ci < 8; ++ci) {
        const int c = ch * 128 + ci * 16 + l16;
        const float bias = b2[t * 256 + c];
#pragma unroll
        for (int r = 0; r < 4; ++r)
          out1[outbase + (size_t)(b0 + m0 + r) * 256 + c] = (acc2[mi][ci][r] + bias) * pv[r];
      }
    }
  }
}

extern "C" void kernel_launch(void* const* d_in, const int* in_sizes, int n_in,
                              void* d_out, int out_size, void* d_ws, size_t ws_size,
                              hipStream_t stream) {
  const float* x  = (const float*)d_in[0];
  const float* Wr = (const float*)d_in[1];
  const float* br = (const float*)d_in[2];
  const float* W1 = (const float*)d_in[3];
  const float* b1 = (const float*)d_in[4];
  const float* W2 = (const float*)d_in[5];
  const float* b2 = (const float*)d_in[6];
  float* out0 = (float*)d_out;                       // [B][T] probs
  float* out1 = out0 + (size_t)B_SZ * T_SZ;          // [T][B][C] preds

  char* ws = (char*)d_ws;
  unsigned short* xb  = (unsigned short*)ws;                                // 16 MiB [B][D]
  unsigned short* w1b = (unsigned short*)(ws + (size_t)16777216);           // 4 MiB  [T][H][D]
  unsigned short* w2b = (unsigned short*)(ws + (size_t)16777216 + 4194304); // 1 MiB  [T][C][H]

  router_cast_kernel<<<B_SZ / 16, 256, 0, stream>>>(x, Wr, br, out0, xb);
  transpose_cast_kernel<<<dim3(D_SZ / 32, T_SZ), 256, 0, stream>>>(W1, w1b, D_SZ, H_SZ, 7);
  transpose_cast_kernel<<<dim3(H_SZ / 32, T_SZ), 256, 0, stream>>>(W2, w2b, H_SZ, C_SZ, 8);
  expert_kernel<<<512, 256, 0, stream>>>(xb, w1b, w2b, b1, b2, out0, out1);
}

// Round 11
// 109.224 us; speedup vs baseline: 5.6855x; 1.0601x over previous
//
#include <hip/hip_runtime.h>

using bf16x8 = __attribute__((ext_vector_type(8))) short;
using f32x4  = __attribute__((ext_vector_type(4))) float;

#define B_SZ 8192
#define D_SZ 1024
#define H_SZ 128
#define C_SZ 256
#define T_SZ 16

__device__ __forceinline__ unsigned short f2bf(float f) {
  unsigned int u = __float_as_uint(f);
  return (unsigned short)((u + 0x7fffu + ((u >> 16) & 1u)) >> 16);
}

// ------- transpose+cast: src[t][R][C] f32 -> dst[t][C][R] bf16 (k-major for MFMA) -------
__global__ __launch_bounds__(256) void transpose_cast_kernel(const float* __restrict__ src,
                                                             unsigned short* __restrict__ dst,
                                                             int R, int C, int cshift) {
  __shared__ float tile[32][257];
  const int t = blockIdx.y;
  const int r0 = blockIdx.x * 32;
  const float* s = src + ((size_t)t * R + r0) * C;
  const int n = 32 * C;
  for (int idx = threadIdx.x; idx < n; idx += 256)
    tile[idx >> cshift][idx & (C - 1)] = s[idx];
  __syncthreads();
  unsigned short* d = dst + (size_t)t * C * R + r0;
  for (int idx = threadIdx.x; idx < n; idx += 256) {
    int cc = idx >> 5, rr = idx & 31;
    d[(size_t)cc * R + rr] = f2bf(tile[rr][cc]);
  }
}

// ------ router + x-cast fused: probs = softmax(x@Wr+br); xb = bf16(x) ------
__global__ __launch_bounds__(256) void router_cast_kernel(const float* __restrict__ x,
                                                          const float* __restrict__ Wr,
                                                          const float* __restrict__ br,
                                                          float* __restrict__ out0,
                                                          unsigned short* __restrict__ xb) {
  const int lane = threadIdx.x & 63;
  const int wid  = threadIdx.x >> 6;
  const int brow = blockIdx.x * 16 + wid * 4;
  float acc[4][16];
#pragma unroll
  for (int r = 0; r < 4; ++r)
#pragma unroll
    for (int tt = 0; tt < 16; ++tt) acc[r][tt] = 0.f;

  for (int it = 0; it < 16; ++it) {
    const int d = it * 64 + lane;
    const float4* w4 = (const float4*)(Wr + (size_t)d * 16);
    float4 wa = w4[0], wb = w4[1], wc = w4[2], wd = w4[3];
    const float wv[16] = {wa.x, wa.y, wa.z, wa.w, wb.x, wb.y, wb.z, wb.w,
                          wc.x, wc.y, wc.z, wc.w, wd.x, wd.y, wd.z, wd.w};
#pragma unroll
    for (int r = 0; r < 4; ++r) {
      const float xv = x[(size_t)(brow + r) * 1024 + d];
      xb[(size_t)(brow + r) * 1024 + d] = f2bf(xv);
#pragma unroll
      for (int tt = 0; tt < 16; ++tt) acc[r][tt] += xv * wv[tt];
    }
  }
#pragma unroll
  for (int off = 32; off >= 1; off >>= 1) {
#pragma unroll
    for (int r = 0; r < 4; ++r)
#pragma unroll
      for (int tt = 0; tt < 16; ++tt) acc[r][tt] += __shfl_xor(acc[r][tt], off);
  }
  if (lane == 0) {
#pragma unroll
    for (int r = 0; r < 4; ++r) {
      float v[16]; float m = -1e30f;
#pragma unroll
      for (int tt = 0; tt < 16; ++tt) { v[tt] = acc[r][tt] + br[tt]; m = fmaxf(m, v[tt]); }
      float ssum = 0.f;
#pragma unroll
      for (int tt = 0; tt < 16; ++tt) { v[tt] = __expf(v[tt] - m); ssum += v[tt]; }
      const float inv = 1.0f / ssum;
      float4* o = (float4*)(out0 + (size_t)(brow + r) * 16);
      o[0] = make_float4(v[0] * inv, v[1] * inv, v[2] * inv, v[3] * inv);
      o[1] = make_float4(v[4] * inv, v[5] * inv, v[6] * inv, v[7] * inv);
      o[2] = make_float4(v[8] * inv, v[9] * inv, v[10] * inv, v[11] * inv);
      o[3] = make_float4(v[12] * inv, v[13] * inv, v[14] * inv, v[15] * inv);
    }
  }
}

// ---------------- fused expert (R2/R8 structure + swapped-fc2 epilogue) ----------------
// fc1: 256m x 128n x 1024k, 2-phase dbuf (stage kt+1 || compute kt), 8 waves, 1 blk/CU.
// fc2: acc2 = mfma(W2, h) -> D-row=c, D-col=m -> float4 out1 stores.
// LDS: sX dbuf 2x32KB | sW dbuf 2x16KB | sH [256][128]bf16 aliases sX region.
#define SW_REG 65536

__global__ __launch_bounds__(512, 2) void expert_kernel(
    const unsigned short* __restrict__ xb, const unsigned short* __restrict__ w1b,
    const unsigned short* __restrict__ w2b, const float* __restrict__ b1,
    const float* __restrict__ b2, const float* __restrict__ probs,
    float* __restrict__ out1) {
  __shared__ __align__(16) char smem[98304];
  const int tid  = threadIdx.x;
  const int lane = tid & 63;
  const int w    = tid >> 6;   // 0..7
  const int l16  = lane & 15;
  const int l4   = lane >> 4;  // 0..3

  // XCD-chunked bijective swizzle (512 = 8 XCD * 64), t fastest within chunk
  const int bid = blockIdx.x;
  const int lid = (bid & 7) * 64 + (bid >> 3);
  const int t   = lid & 15;
  const int b0  = (lid >> 4) * 256;

  // ---- staging precompute: 6 x 16B gload_lds per thread per kt ----
  const unsigned short* gp[6];
  unsigned int ldo[6];
#pragma unroll
  for (int it = 0; it < 6; ++it) {
    if (it < 4) {
      const unsigned int o = (unsigned int)w * 4096u + (unsigned int)it * 1024u + (unsigned int)lane * 16u;
      const int row = (int)(o >> 7);
      const int cb  = (int)((o & 127u) ^ (((unsigned)row & 7u) << 4));
      gp[it]  = xb + (size_t)(b0 + row) * 1024 + (cb >> 1);
      ldo[it] = o;
    } else {
      const unsigned int o = (unsigned int)w * 2048u + (unsigned int)(it - 4) * 1024u + (unsigned int)lane * 16u;
      const int row = (int)(o >> 7);
      const int cb  = (int)((o & 127u) ^ (((unsigned)row & 7u) << 4));
      gp[it]  = w1b + (size_t)(t * 128 + row) * 1024 + (cb >> 1);
      ldo[it] = o;
    }
  }

#define STAGE(curbuf, kt)                                                              \
  {                                                                                    \
    _Pragma("unroll")                                                                  \
    for (int it = 0; it < 6; ++it) {                                                   \
      const unsigned short* g = gp[it] + (kt) * 64;                                    \
      char* dd = smem + (it < 4 ? (curbuf) * 32768 + (int)ldo[it]                      \
                                : SW_REG + (curbuf) * 16384 + (int)ldo[it]);           \
      __builtin_amdgcn_global_load_lds(                                                \
          (const __attribute__((address_space(1))) unsigned int*)g,                    \
          (__attribute__((address_space(3))) unsigned int*)dd, 16, 0, 0);              \
    }                                                                                  \
  }

  // fc1 wave grid: wn (2 n-halves of 64) x wm (4 m-quads of 64)
  const int wn = w & 1;
  const int wm = w >> 1;
  f32x4 acc1[4][4] = {};

#define FC1_COMPUTE(curbuf)                                                            \
  {                                                                                    \
    const int bx_base = (curbuf) * 32768;                                              \
    const int aw_base = SW_REG + (curbuf) * 16384;                                     \
    _Pragma("unroll")                                                                  \
    for (int ks = 0; ks < 2; ++ks) {                                                   \
      const int cb = ks * 64 + l4 * 16;                                                \
      bf16x8 aw[4], bx[4];                                                             \
      _Pragma("unroll")                                                                \
      for (int ni = 0; ni < 4; ++ni) {                                                 \
        const int row = wn * 64 + ni * 16 + l16;                                       \
        aw[ni] = *(const bf16x8*)(smem + aw_base + (row << 7) + (cb ^ ((row & 7) << 4)));\
      }                                                                                \
      _Pragma("unroll")                                                                \
      for (int mi = 0; mi < 4; ++mi) {                                                 \
        const int row = wm * 64 + mi * 16 + l16;                                       \
        bx[mi] = *(const bf16x8*)(smem + bx_base + (row << 7) + (cb ^ ((row & 7) << 4)));\
      }                                                                                \
      _Pragma("unroll")                                                                \
      for (int ni = 0; ni < 4; ++ni)                                                   \
        _Pragma("unroll")                                                              \
        for (int mi = 0; mi < 4; ++mi)                                                 \
          acc1[ni][mi] = __builtin_amdgcn_mfma_f32_16x16x32_bf16(aw[ni], bx[mi], acc1[ni][mi], 0, 0, 0); \
    }                                                                                  \
  }

  STAGE(0, 0);
  __syncthreads();
  int cur = 0;
  for (int kt = 0; kt < 15; ++kt) {
    STAGE(cur ^ 1, kt + 1);
    FC1_COMPUTE(cur);
    __syncthreads();
    cur ^= 1;
  }
  FC1_COMPUTE(cur);
  __syncthreads();  // all waves done reading sX/sW before sH (aliased) writes

  // fc1 epilogue: +b1, relu, cvt bf16, write hT -> sH[m][k=n] (swizzled, 8B stores)
#pragma unroll
  for (int ni = 0; ni < 4; ++ni) {
    const int n0 = wn * 64 + ni * 16 + l4 * 4;
    float bb[4];
#pragma unroll
    for (int r = 0; r < 4; ++r) bb[r] = b1[t * 128 + n0 + r];
#pragma unroll
    for (int mi = 0; mi < 4; ++mi) {
      const int m = wm * 64 + mi * 16 + l16;
      unsigned int pk[2];
#pragma unroll
      for (int h = 0; h < 2; ++h) {
        float v0 = fmaxf(acc1[ni][mi][2 * h + 0] + bb[2 * h + 0], 0.f);
        float v1 = fmaxf(acc1[ni][mi][2 * h + 1] + bb[2 * h + 1], 0.f);
        pk[h] = (unsigned int)f2bf(v0) | ((unsigned int)f2bf(v1) << 16);
      }
      const int byte = (m << 8) + ((n0 * 2) ^ ((m & 7) << 4));
      *(uint2*)(smem + byte) = make_uint2(pk[0], pk[1]);
    }
  }
  __syncthreads();

  // fc2: SWAPPED operands -> D-row=c, D-col=m. acc2[mi][ci]: c=wc*128+ci*16+l4*4+r, m=wm2*64+mi*16+l16
  const int wm2 = w >> 1;
  const int wc  = w & 1;
  f32x4 acc2[4][8] = {};
  const unsigned short* w2t = w2b + (size_t)t * C_SZ * H_SZ;

#pragma unroll
  for (int ks = 0; ks < 4; ++ks) {
    const int cb = ks * 64 + l4 * 16;
    bf16x8 ah[4];
#pragma unroll
    for (int mi = 0; mi < 4; ++mi) {
      const int row = wm2 * 64 + mi * 16 + l16;
      ah[mi] = *(const bf16x8*)(smem + (row << 8) + (cb ^ ((row & 7) << 4)));
    }
#pragma unroll
    for (int ci = 0; ci < 8; ++ci) {
      const int c = wc * 128 + ci * 16 + l16;
      bf16x8 bw = *(const bf16x8*)(w2t + (size_t)c * 128 + ks * 32 + l4 * 8);
#pragma unroll
      for (int mi = 0; mi < 4; ++mi)
        acc2[mi][ci] = __builtin_amdgcn_mfma_f32_16x16x32_bf16(bw, ah[mi], acc2[mi][ci], 0, 0, 0);
    }
  }

  // fc2 epilogue: +b2 (float4), * probs (1 scalar/lane/mi), float4 stores
  const size_t outbase = (size_t)t * (size_t)(B_SZ * C_SZ);
#pragma unroll
  for (int mi = 0; mi < 4; ++mi) {
    const int m = wm2 * 64 + mi * 16 + l16;
    const float pv = probs[(size_t)(b0 + m) * 16 + t];
    float* orow = out1 + outbase + (size_t)(b0 + m) * 256;
#pragma unroll
    for (int ci = 0; ci < 8; ++ci) {
      const int c0 = wc * 128 + ci * 16 + l4 * 4;
      const float4 bias = *(const float4*)(b2 + t * 256 + c0);
      float4 o;
      o.x = (acc2[mi][ci][0] + bias.x) * pv;
      o.y = (acc2[mi][ci][1] + bias.y) * pv;
      o.z = (acc2[mi][ci][2] + bias.z) * pv;
      o.w = (acc2[mi][ci][3] + bias.w) * pv;
      *(float4*)(orow + c0) = o;
    }
  }
}

extern "C" void kernel_launch(void* const* d_in, const int* in_sizes, int n_in,
                              void* d_out, int out_size, void* d_ws, size_t ws_size,
                              hipStream_t stream) {
  const float* x  = (const float*)d_in[0];
  const float* Wr = (const float*)d_in[1];
  const float* br = (const float*)d_in[2];
  const float* W1 = (const float*)d_in[3];
  const float* b1 = (const float*)d_in[4];
  const float* W2 = (const float*)d_in[5];
  const float* b2 = (const float*)d_in[6];
  float* out0 = (float*)d_out;                       // [B][T] probs
  float* out1 = out0 + (size_t)B_SZ * T_SZ;          // [T][B][C] preds

  char* ws = (char*)d_ws;
  unsigned short* xb  = (unsigned short*)ws;                                // 16 MiB [B][D]
  unsigned short* w1b = (unsigned short*)(ws + (size_t)16777216);           // 4 MiB  [T][H][D]
  unsigned short* w2b = (unsigned short*)(ws + (size_t)16777216 + 4194304); // 1 MiB  [T][C][H]

  router_cast_kernel<<<B_SZ / 16, 256, 0, stream>>>(x, Wr, br, out0, xb);
  transpose_cast_kernel<<<dim3(D_SZ / 32, T_SZ), 256, 0, stream>>>(W1, w1b, D_SZ, H_SZ, 7);
  transpose_cast_kernel<<<dim3(H_SZ / 32, T_SZ), 256, 0, stream>>>(W2, w2b, H_SZ, C_SZ, 8);
  expert_kernel<<<512, 512, 0, stream>>>(xb, w1b, w2b, b1, b2, out0, out1);
}